// Round 1
// 577.516 us; speedup vs baseline: 1.1751x; 1.1751x over previous
//
#include <hip/hip_runtime.h>
#include <math.h>

#define HEADS 4
#define HID 32
#define FEAT 128   // HEADS*HID == IN == hidden width everywhere
#define SLOPE 0.2f

typedef __attribute__((ext_vector_type(8))) short frag_ab;  // 8 bf16
typedef __attribute__((ext_vector_type(4))) float frag_cd;  // 4 fp32
typedef __attribute__((ext_vector_type(8))) _Float16 half8; // 16B of fp16

__device__ inline unsigned short f2bf(float f) {            // RNE fp32->bf16 bits
    unsigned u = __float_as_uint(f);
    unsigned r = u + 0x7FFFu + ((u >> 16) & 1u);
    return (unsigned short)(r >> 16);
}
__device__ inline float bf2f(unsigned short b) {
    return __uint_as_float(((unsigned)b) << 16);
}

// ---------------------------------------------------------------------------
// CSR build
// ---------------------------------------------------------------------------

__global__ void hist_kernel(const int* __restrict__ edge_index, int* __restrict__ deg, int E) {
    int e = blockIdx.x * 256 + threadIdx.x;
    if (e < E) atomicAdd(&deg[edge_index[E + e]], 1);
}

#define SCAN_BLK 1024
#define SCAN_CHUNK 4
#define SCAN_TILE (SCAN_BLK * SCAN_CHUNK)

__global__ __launch_bounds__(SCAN_BLK) void scan_partial(const int* __restrict__ deg,
                                                         int* __restrict__ bsum, int Nn) {
    __shared__ int red[SCAN_BLK];
    int t = threadIdx.x;
    int base = blockIdx.x * SCAN_TILE + t * SCAN_CHUNK;
    int s = 0;
#pragma unroll
    for (int i = 0; i < SCAN_CHUNK; i++) {
        int idx = base + i;
        if (idx < Nn) s += deg[idx] + 1;
    }
    red[t] = s;
    __syncthreads();
    for (int off = SCAN_BLK / 2; off >= 1; off >>= 1) {
        if (t < off) red[t] += red[t + off];
        __syncthreads();
    }
    if (t == 0) bsum[blockIdx.x] = red[0];
}

__global__ __launch_bounds__(64) void scan_bsum(int* __restrict__ bsum, int nb) {
    int t = threadIdx.x;
    int v = (t < nb) ? bsum[t] : 0;
    int orig = v;
#pragma unroll
    for (int off = 1; off < 64; off <<= 1) {
        int u = __shfl_up(v, off);
        if (t >= off) v += u;
    }
    if (t < nb) bsum[t] = v - orig;
}

__global__ __launch_bounds__(SCAN_BLK) void scan_final(const int* __restrict__ deg,
                                                       const int* __restrict__ bsum,
                                                       int* __restrict__ rowptr,
                                                       int* __restrict__ cursor, int Nn) {
    __shared__ int sums[SCAN_BLK];
    int t = threadIdx.x;
    int base = blockIdx.x * SCAN_TILE + t * SCAN_CHUNK;
    int loc[SCAN_CHUNK];
    int s = 0;
#pragma unroll
    for (int i = 0; i < SCAN_CHUNK; i++) {
        int idx = base + i;
        int d = (idx < Nn) ? deg[idx] + 1 : 0;
        loc[i] = s;
        s += d;
    }
    sums[t] = s;
    __syncthreads();
    for (int off = 1; off < SCAN_BLK; off <<= 1) {
        int v = (t >= off) ? sums[t - off] : 0;
        __syncthreads();
        sums[t] += v;
        __syncthreads();
    }
    int texcl = (t == 0) ? 0 : sums[t - 1];
    int offn = bsum[blockIdx.x] + texcl;
#pragma unroll
    for (int i = 0; i < SCAN_CHUNK; i++) {
        int idx = base + i;
        if (idx < Nn) {
            int v = offn + loc[i];
            rowptr[idx] = v;
            cursor[idx] = v;
        }
    }
    if (blockIdx.x == gridDim.x - 1 && t == SCAN_BLK - 1)
        rowptr[Nn] = offn + s;
}

__global__ void scatter_kernel(const int* __restrict__ edge_index, int* __restrict__ cursor,
                               int* __restrict__ ssorted, int E, int Nn) {
    int e = blockIdx.x * 256 + threadIdx.x;
    if (e < E) {
        int d = edge_index[E + e];
        int srcv = edge_index[e];
        int pos = atomicAdd(&cursor[d], 1);
        ssorted[pos] = srcv;
    } else if (e < E + Nn) {
        int i = e - E;
        int pos = atomicAdd(&cursor[i], 1);
        ssorted[pos] = i;
    }
}

// ---------------------------------------------------------------------------
// W prep, all 3 layers in one launch: split fp32 W[k][c] into bf16 hi/lo,
// fragment-friendly transposed: wt[L][ (g*128 + c)*8 + j ] = W_L[g*8 + j][c]
// ---------------------------------------------------------------------------
__global__ void prep_w3(const float* __restrict__ W1, const float* __restrict__ W2,
                        const float* __restrict__ W3,
                        unsigned short* __restrict__ wt_hi,
                        unsigned short* __restrict__ wt_lo) {
    int idx = blockIdx.x * 256 + threadIdx.x;
    if (idx >= 3 * FEAT * FEAT) return;
    int L = idx / (FEAT * FEAT);
    int r = idx - L * FEAT * FEAT;
    const float* W = (L == 0) ? W1 : (L == 1) ? W2 : W3;
    int c = r >> 7, k = r & 127;
    float v = W[(size_t)k * FEAT + c];
    unsigned short hi = f2bf(v);
    unsigned short lo = f2bf(v - bf2f(hi));
    int g = k >> 3, j = k & 7;
    size_t o = (size_t)L * FEAT * FEAT + ((size_t)g * FEAT + c) * 8 + j;
    wt_hi[o] = hi;
    wt_lo[o] = lo;
}

// ---------------------------------------------------------------------------
// GEMM via MFMA 16x16x32 bf16 (split hi/lo = fp32-level accuracy) with fused
// epilogue: fp16 feature matrix xw + per-node attn score halves.
// xw is consumed ONLY by edge_agg (gather) -> fp16 halves the gather bytes.
// ---------------------------------------------------------------------------
__global__ __launch_bounds__(256) void gemm_mfma(const float* __restrict__ A,
                                                 const unsigned short* __restrict__ wt_hi,
                                                 const unsigned short* __restrict__ wt_lo,
                                                 const float* __restrict__ a_s,
                                                 const float* __restrict__ a_d,
                                                 _Float16* __restrict__ xw,
                                                 float* __restrict__ ssrc,
                                                 float* __restrict__ sdst,
                                                 int nrows) {
    int tid = threadIdx.x;
    int wave = tid >> 6, lane = tid & 63;
    int r = lane & 15;     // A-row (load) / D-col (store) index within tile
    int q = lane >> 4;     // k-quad (A/B) / row-quad (D)
    int rowbase = blockIdx.x * 64 + wave * 16;

    int arow = rowbase + r;
    if (arow >= nrows) arow = nrows - 1;

    frag_cd acc[8];
#pragma unroll
    for (int ct = 0; ct < 8; ct++) acc[ct] = (frag_cd){0.f, 0.f, 0.f, 0.f};

    const float* arowp = A + (size_t)arow * FEAT;

#pragma unroll
    for (int k0 = 0; k0 < FEAT; k0 += 32) {
        int kk = k0 + q * 8;
        float4 a0 = *(const float4*)(arowp + kk);
        float4 a1 = *(const float4*)(arowp + kk + 4);
        float av[8] = {a0.x, a0.y, a0.z, a0.w, a1.x, a1.y, a1.z, a1.w};
        frag_ab ahi, alo;
#pragma unroll
        for (int j = 0; j < 8; j++) {
            unsigned short h = f2bf(av[j]);
            ahi[j] = (short)h;
            alo[j] = (short)f2bf(av[j] - bf2f(h));
        }
        int g = kk >> 3;
#pragma unroll
        for (int ct = 0; ct < 8; ct++) {
            int c = ct * 16 + r;
            const frag_ab bhi = *(const frag_ab*)(wt_hi + ((size_t)g * FEAT + c) * 8);
            const frag_ab blo = *(const frag_ab*)(wt_lo + ((size_t)g * FEAT + c) * 8);
            acc[ct] = __builtin_amdgcn_mfma_f32_16x16x32_bf16(ahi, bhi, acc[ct], 0, 0, 0);
            acc[ct] = __builtin_amdgcn_mfma_f32_16x16x32_bf16(ahi, blo, acc[ct], 0, 0, 0);
            acc[ct] = __builtin_amdgcn_mfma_f32_16x16x32_bf16(alo, bhi, acc[ct], 0, 0, 0);
        }
    }

    float asv[8], adv[8];
#pragma unroll
    for (int ct = 0; ct < 8; ct++) {
        asv[ct] = a_s[ct * 16 + r];
        adv[ct] = a_d[ct * 16 + r];
    }

    // D layout: col = ct*16 + r, row = q*4 + gi  [m89-verified]
#pragma unroll
    for (int gi = 0; gi < 4; gi++) {
        int rr = rowbase + q * 4 + gi;
        bool ok = rr < nrows;
        float ps[4] = {0.f, 0.f, 0.f, 0.f}, pd[4] = {0.f, 0.f, 0.f, 0.f};
#pragma unroll
        for (int ct = 0; ct < 8; ct++) {
            float v = acc[ct][gi];
            if (ok) xw[(size_t)rr * FEAT + ct * 16 + r] = (_Float16)v;
            ps[ct >> 1] += v * asv[ct];
            pd[ct >> 1] += v * adv[ct];
        }
#pragma unroll
        for (int h = 0; h < 4; h++) {
#pragma unroll
            for (int m = 1; m < 16; m <<= 1) {
                ps[h] += __shfl_xor(ps[h], m);
                pd[h] += __shfl_xor(pd[h], m);
            }
        }
        if (ok) {
            if (r < 4)      ssrc[rr * HEADS + r] = ps[r];
            else if (r < 8) sdst[rr * HEADS + (r - 4)] = pd[r - 4];
        }
    }
}

// ---------------------------------------------------------------------------
// Single-pass edge softmax+aggregate, one wave per node, 4 edge slots.
// lane = slot(=lane/16) x q(=lane%16, channel octet 8q..8q+7).
// Per edge: 16 lanes x 16 B (fp16) = full 256 B row; 4 edges in flight per
// wave. No max-subtraction (scores O(+-6), fp32 exp safe). Slot-fold:
// shfl_xor 16,32. Head-mean (final): shfl_xor 4,8. Zero LDS, zero barriers.
// Feature gather is fp16 (half the bytes of fp32); accumulate fp32 via
// v_fma_mix. Output (bufB / final out) stays fp32.
// ---------------------------------------------------------------------------
__global__ __launch_bounds__(256) void edge_agg(const _Float16* __restrict__ xw,
                                                const float* __restrict__ ssrc,
                                                const float* __restrict__ sdst,
                                                const int* __restrict__ rowptr,
                                                const int* __restrict__ ssorted,
                                                const float* __restrict__ bias,
                                                float* __restrict__ out,
                                                int final_layer, int Nn) {
    int wid = blockIdx.x * 4 + (threadIdx.x >> 6);   // node index
    if (wid >= Nn) return;
    int lane = threadIdx.x & 63;
    int slot = lane >> 4;       // edge slot 0..3
    int q = lane & 15;          // channel octet (channels 8q..8q+7)
    int qh = q >> 2;            // head of this octet

    int beg = rowptr[wid], end = rowptr[wid + 1];
    float sdh = sdst[wid * HEADS + qh];

    float4 a0 = make_float4(0.f, 0.f, 0.f, 0.f);
    float4 a1 = make_float4(0.f, 0.f, 0.f, 0.f);
    float den = 0.f;

    for (int i = beg + slot; i < end; i += 4) {
        int s = ssorted[i];                       // broadcast within slot
        float v = ssrc[s * HEADS + qh] + sdh;
        v = v > 0.f ? v : SLOPE * v;
        float w = __expf(v);                      // safe: |v| ~ O(6)
        den += w;
        const half8 hv = *(const half8*)(xw + (size_t)s * FEAT + q * 8);
        a0.x += w * (float)hv[0]; a0.y += w * (float)hv[1];
        a0.z += w * (float)hv[2]; a0.w += w * (float)hv[3];
        a1.x += w * (float)hv[4]; a1.y += w * (float)hv[5];
        a1.z += w * (float)hv[6]; a1.w += w * (float)hv[7];
    }

    // fold the 4 edge slots (lane bits 4,5)
#pragma unroll
    for (int m = 16; m <= 32; m <<= 1) {
        a0.x += __shfl_xor(a0.x, m); a0.y += __shfl_xor(a0.y, m);
        a0.z += __shfl_xor(a0.z, m); a0.w += __shfl_xor(a0.w, m);
        a1.x += __shfl_xor(a1.x, m); a1.y += __shfl_xor(a1.y, m);
        a1.z += __shfl_xor(a1.z, m); a1.w += __shfl_xor(a1.w, m);
        den  += __shfl_xor(den, m);
    }

    float inv = 1.f / den;                        // den>0 (self loop); per-head
    a0.x *= inv; a0.y *= inv; a0.z *= inv; a0.w *= inv;
    a1.x *= inv; a1.y *= inv; a1.z *= inv; a1.w *= inv;

    if (!final_layer) {
        if (lane < 16) {
            const float4 b0 = *(const float4*)(bias + q * 8);
            const float4 b1 = *(const float4*)(bias + q * 8 + 4);
            float4 r0, r1;
            r0.x = a0.x + b0.x; r0.y = a0.y + b0.y; r0.z = a0.z + b0.z; r0.w = a0.w + b0.w;
            r1.x = a1.x + b1.x; r1.y = a1.y + b1.y; r1.z = a1.z + b1.z; r1.w = a1.w + b1.w;
            r0.x = r0.x > 0.f ? r0.x : expm1f(r0.x);
            r0.y = r0.y > 0.f ? r0.y : expm1f(r0.y);
            r0.z = r0.z > 0.f ? r0.z : expm1f(r0.z);
            r0.w = r0.w > 0.f ? r0.w : expm1f(r0.w);
            r1.x = r1.x > 0.f ? r1.x : expm1f(r1.x);
            r1.y = r1.y > 0.f ? r1.y : expm1f(r1.y);
            r1.z = r1.z > 0.f ? r1.z : expm1f(r1.z);
            r1.w = r1.w > 0.f ? r1.w : expm1f(r1.w);
            float4* op = (float4*)(out + (size_t)wid * FEAT + q * 8);
            op[0] = r0; op[1] = r1;
        }
    } else {
        // head-mean: same within-head channels sit at lanes q, q^4, q^8 (bits 2,3)
#pragma unroll
        for (int m = 4; m <= 8; m <<= 1) {
            a0.x += __shfl_xor(a0.x, m); a0.y += __shfl_xor(a0.y, m);
            a0.z += __shfl_xor(a0.z, m); a0.w += __shfl_xor(a0.w, m);
            a1.x += __shfl_xor(a1.x, m); a1.y += __shfl_xor(a1.y, m);
            a1.z += __shfl_xor(a1.z, m); a1.w += __shfl_xor(a1.w, m);
        }
        if (lane < 4) {
            const float4 b0 = *(const float4*)(bias + q * 8);
            const float4 b1 = *(const float4*)(bias + q * 8 + 4);
            float4 r0, r1;
            r0.x = a0.x * 0.25f + b0.x; r0.y = a0.y * 0.25f + b0.y;
            r0.z = a0.z * 0.25f + b0.z; r0.w = a0.w * 0.25f + b0.w;
            r1.x = a1.x * 0.25f + b1.x; r1.y = a1.y * 0.25f + b1.y;
            r1.z = a1.z * 0.25f + b1.z; r1.w = a1.w * 0.25f + b1.w;
            float4* op = (float4*)(out + (size_t)wid * HID + q * 8);
            op[0] = r0; op[1] = r1;
        }
    }
}

// ---------------------------------------------------------------------------
// Launch
// ---------------------------------------------------------------------------
extern "C" void kernel_launch(void* const* d_in, const int* in_sizes, int n_in,
                              void* d_out, int out_size, void* d_ws, size_t ws_size,
                              hipStream_t stream) {
    const float* x   = (const float*)d_in[0];
    const int* eidx  = (const int*)d_in[1];
    const float* W1  = (const float*)d_in[2];
    const float* as1 = (const float*)d_in[3];
    const float* ad1 = (const float*)d_in[4];
    const float* b1  = (const float*)d_in[5];
    const float* W2  = (const float*)d_in[6];
    const float* as2 = (const float*)d_in[7];
    const float* ad2 = (const float*)d_in[8];
    const float* b2  = (const float*)d_in[9];
    const float* W3  = (const float*)d_in[10];
    const float* as3 = (const float*)d_in[11];
    const float* ad3 = (const float*)d_in[12];
    const float* b3  = (const float*)d_in[13];

    const int Nn = in_sizes[0] / FEAT;   // 100000
    const int E  = in_sizes[1] / 2;      // 1200000
    const int EP = E + Nn;

    char* w = (char*)d_ws;
    size_t off = 0;
    auto alloc = [&](size_t bytes) {
        void* p = w + off;
        off += (bytes + 255) & ~(size_t)255;
        return p;
    };
    float* bufB   = (float*)alloc((size_t)Nn * FEAT * 4);     // inter-layer fp32
    _Float16* xwh = (_Float16*)alloc((size_t)Nn * FEAT * 2);  // post-GEMM features (fp16)
    float* ssrc   = (float*)alloc((size_t)Nn * HEADS * 4);
    float* sdst   = (float*)alloc((size_t)Nn * HEADS * 4);
    int*   rowptr = (int*)alloc((size_t)(Nn + 1) * 4);
    int*   cursor = (int*)alloc((size_t)Nn * 4);
    int*   deg    = (int*)alloc((size_t)Nn * 4);
    int*   ssort  = (int*)alloc((size_t)EP * 4);
    int*   bsum   = (int*)alloc(64 * 4);
    unsigned short* wth = (unsigned short*)alloc((size_t)3 * FEAT * FEAT * 2);
    unsigned short* wtl = (unsigned short*)alloc((size_t)3 * FEAT * FEAT * 2);
    (void)ws_size;

    // ---- CSR build + all-layer W prep (once)
    hipMemsetAsync(deg, 0, (size_t)Nn * 4, stream);
    hist_kernel<<<(E + 255) / 256, 256, 0, stream>>>(eidx, deg, E);
    prep_w3<<<(3 * FEAT * FEAT + 255) / 256, 256, 0, stream>>>(W1, W2, W3, wth, wtl);
    int nscan = (Nn + SCAN_TILE - 1) / SCAN_TILE;
    scan_partial<<<nscan, SCAN_BLK, 0, stream>>>(deg, bsum, Nn);
    scan_bsum<<<1, 64, 0, stream>>>(bsum, nscan);
    scan_final<<<nscan, SCAN_BLK, 0, stream>>>(deg, bsum, rowptr, cursor, Nn);
    scatter_kernel<<<(EP + 255) / 256, 256, 0, stream>>>(eidx, cursor, ssort, E, Nn);

    const int gemm_grid = (Nn + 63) / 64;
    const int agg_grid  = (Nn + 3) / 4;

    const float* as[3] = {as1, as2, as3};
    const float* ad[3] = {ad1, ad2, ad3};
    const float* bs[3] = {b1, b2, b3};

    const float* cur_in = x;
    for (int L = 0; L < 3; L++) {
        float* nxt = (L == 2) ? (float*)d_out : bufB;
        gemm_mfma<<<gemm_grid, 256, 0, stream>>>(cur_in,
                                                 wth + (size_t)L * FEAT * FEAT,
                                                 wtl + (size_t)L * FEAT * FEAT,
                                                 as[L], ad[L], xwh, ssrc, sdst, Nn);
        edge_agg<<<agg_grid, 256, 0, stream>>>(xwh, ssrc, sdst, rowptr, ssort,
                                               bs[L], nxt, L == 2, Nn);
        cur_in = bufB;
    }
}

// Round 2
// 507.935 us; speedup vs baseline: 1.3361x; 1.1370x over previous
//
#include <hip/hip_runtime.h>
#include <math.h>

#define HEADS 4
#define HID 32
#define FEAT 128   // HEADS*HID == IN == hidden width everywhere
#define SLOPE 0.2f

typedef __attribute__((ext_vector_type(8))) short frag_ab;  // 8 bf16
typedef __attribute__((ext_vector_type(4))) float frag_cd;  // 4 fp32
typedef __attribute__((ext_vector_type(8))) _Float16 half8; // 16B of fp16

__device__ inline unsigned short f2bf(float f) {            // RNE fp32->bf16 bits
    unsigned u = __float_as_uint(f);
    unsigned r = u + 0x7FFFu + ((u >> 16) & 1u);
    return (unsigned short)(r >> 16);
}
__device__ inline float bf2f(unsigned short b) {
    return __uint_as_float(((unsigned)b) << 16);
}

// ---------------------------------------------------------------------------
// CSR build. hist's atomicAdd return value IS the edge's rank within its
// destination bucket -> scatter needs no atomic (no dependent atomic->store
// chain). Self-loops are folded into edge_agg directly (no CSR slot).
// ---------------------------------------------------------------------------

__global__ void hist_kernel(const int* __restrict__ edge_index, int* __restrict__ deg,
                            int* __restrict__ rank, int E) {
    int e = blockIdx.x * 256 + threadIdx.x;
    if (e < E) rank[e] = atomicAdd(&deg[edge_index[E + e]], 1);
}

#define SCAN_BLK 1024
#define SCAN_CHUNK 4
#define SCAN_TILE (SCAN_BLK * SCAN_CHUNK)

__global__ __launch_bounds__(SCAN_BLK) void scan_partial(const int* __restrict__ deg,
                                                         int* __restrict__ bsum, int Nn) {
    __shared__ int red[SCAN_BLK];
    int t = threadIdx.x;
    int base = blockIdx.x * SCAN_TILE + t * SCAN_CHUNK;
    int s = 0;
#pragma unroll
    for (int i = 0; i < SCAN_CHUNK; i++) {
        int idx = base + i;
        if (idx < Nn) s += deg[idx];
    }
    red[t] = s;
    __syncthreads();
    for (int off = SCAN_BLK / 2; off >= 1; off >>= 1) {
        if (t < off) red[t] += red[t + off];
        __syncthreads();
    }
    if (t == 0) bsum[blockIdx.x] = red[0];
}

__global__ __launch_bounds__(64) void scan_bsum(int* __restrict__ bsum, int nb) {
    int t = threadIdx.x;
    int v = (t < nb) ? bsum[t] : 0;
    int orig = v;
#pragma unroll
    for (int off = 1; off < 64; off <<= 1) {
        int u = __shfl_up(v, off);
        if (t >= off) v += u;
    }
    if (t < nb) bsum[t] = v - orig;
}

__global__ __launch_bounds__(SCAN_BLK) void scan_final(const int* __restrict__ deg,
                                                       const int* __restrict__ bsum,
                                                       int* __restrict__ rowptr, int Nn) {
    __shared__ int sums[SCAN_BLK];
    int t = threadIdx.x;
    int base = blockIdx.x * SCAN_TILE + t * SCAN_CHUNK;
    int loc[SCAN_CHUNK];
    int s = 0;
#pragma unroll
    for (int i = 0; i < SCAN_CHUNK; i++) {
        int idx = base + i;
        int d = (idx < Nn) ? deg[idx] : 0;
        loc[i] = s;
        s += d;
    }
    sums[t] = s;
    __syncthreads();
    for (int off = 1; off < SCAN_BLK; off <<= 1) {
        int v = (t >= off) ? sums[t - off] : 0;
        __syncthreads();
        sums[t] += v;
        __syncthreads();
    }
    int texcl = (t == 0) ? 0 : sums[t - 1];
    int offn = bsum[blockIdx.x] + texcl;
#pragma unroll
    for (int i = 0; i < SCAN_CHUNK; i++) {
        int idx = base + i;
        if (idx < Nn) rowptr[idx] = offn + loc[i];
    }
    if (blockIdx.x == gridDim.x - 1 && t == SCAN_BLK - 1)
        rowptr[Nn] = offn + s;
}

// No atomic: position = rowptr[dst] + precomputed rank. Bijective per bucket.
__global__ void scatter_kernel(const int* __restrict__ edge_index,
                               const int* __restrict__ rank,
                               const int* __restrict__ rowptr,
                               int* __restrict__ ssorted, int E) {
    int e = blockIdx.x * 256 + threadIdx.x;
    if (e < E) {
        int d = edge_index[E + e];
        ssorted[rowptr[d] + rank[e]] = edge_index[e];
    }
}

// ---------------------------------------------------------------------------
// W prep, all 3 layers in one launch: split fp32 W[k][c] into bf16 hi/lo,
// fragment-friendly transposed: wt[L][ (g*128 + c)*8 + j ] = W_L[g*8 + j][c]
// ---------------------------------------------------------------------------
__global__ void prep_w3(const float* __restrict__ W1, const float* __restrict__ W2,
                        const float* __restrict__ W3,
                        unsigned short* __restrict__ wt_hi,
                        unsigned short* __restrict__ wt_lo) {
    int idx = blockIdx.x * 256 + threadIdx.x;
    if (idx >= 3 * FEAT * FEAT) return;
    int L = idx / (FEAT * FEAT);
    int r = idx - L * FEAT * FEAT;
    const float* W = (L == 0) ? W1 : (L == 1) ? W2 : W3;
    int c = r >> 7, k = r & 127;
    float v = W[(size_t)k * FEAT + c];
    unsigned short hi = f2bf(v);
    unsigned short lo = f2bf(v - bf2f(hi));
    int g = k >> 3, j = k & 7;
    size_t o = (size_t)L * FEAT * FEAT + ((size_t)g * FEAT + c) * 8 + j;
    wt_hi[o] = hi;
    wt_lo[o] = lo;
}

// ---------------------------------------------------------------------------
// GEMM via MFMA 16x16x32 bf16 (split hi/lo = fp32-level accuracy) with fused
// epilogue: fp16 feature matrix xw + per-node attn score halves.
// xw is consumed ONLY by edge_agg (gather) -> fp16 halves the gather bytes.
// ---------------------------------------------------------------------------
__global__ __launch_bounds__(256) void gemm_mfma(const float* __restrict__ A,
                                                 const unsigned short* __restrict__ wt_hi,
                                                 const unsigned short* __restrict__ wt_lo,
                                                 const float* __restrict__ a_s,
                                                 const float* __restrict__ a_d,
                                                 _Float16* __restrict__ xw,
                                                 float* __restrict__ ssrc,
                                                 float* __restrict__ sdst,
                                                 int nrows) {
    int tid = threadIdx.x;
    int wave = tid >> 6, lane = tid & 63;
    int r = lane & 15;     // A-row (load) / D-col (store) index within tile
    int q = lane >> 4;     // k-quad (A/B) / row-quad (D)
    int rowbase = blockIdx.x * 64 + wave * 16;

    int arow = rowbase + r;
    if (arow >= nrows) arow = nrows - 1;

    frag_cd acc[8];
#pragma unroll
    for (int ct = 0; ct < 8; ct++) acc[ct] = (frag_cd){0.f, 0.f, 0.f, 0.f};

    const float* arowp = A + (size_t)arow * FEAT;

#pragma unroll
    for (int k0 = 0; k0 < FEAT; k0 += 32) {
        int kk = k0 + q * 8;
        float4 a0 = *(const float4*)(arowp + kk);
        float4 a1 = *(const float4*)(arowp + kk + 4);
        float av[8] = {a0.x, a0.y, a0.z, a0.w, a1.x, a1.y, a1.z, a1.w};
        frag_ab ahi, alo;
#pragma unroll
        for (int j = 0; j < 8; j++) {
            unsigned short h = f2bf(av[j]);
            ahi[j] = (short)h;
            alo[j] = (short)f2bf(av[j] - bf2f(h));
        }
        int g = kk >> 3;
#pragma unroll
        for (int ct = 0; ct < 8; ct++) {
            int c = ct * 16 + r;
            const frag_ab bhi = *(const frag_ab*)(wt_hi + ((size_t)g * FEAT + c) * 8);
            const frag_ab blo = *(const frag_ab*)(wt_lo + ((size_t)g * FEAT + c) * 8);
            acc[ct] = __builtin_amdgcn_mfma_f32_16x16x32_bf16(ahi, bhi, acc[ct], 0, 0, 0);
            acc[ct] = __builtin_amdgcn_mfma_f32_16x16x32_bf16(ahi, blo, acc[ct], 0, 0, 0);
            acc[ct] = __builtin_amdgcn_mfma_f32_16x16x32_bf16(alo, bhi, acc[ct], 0, 0, 0);
        }
    }

    float asv[8], adv[8];
#pragma unroll
    for (int ct = 0; ct < 8; ct++) {
        asv[ct] = a_s[ct * 16 + r];
        adv[ct] = a_d[ct * 16 + r];
    }

    // D layout: col = ct*16 + r, row = q*4 + gi  [m89-verified]
#pragma unroll
    for (int gi = 0; gi < 4; gi++) {
        int rr = rowbase + q * 4 + gi;
        bool ok = rr < nrows;
        float ps[4] = {0.f, 0.f, 0.f, 0.f}, pd[4] = {0.f, 0.f, 0.f, 0.f};
#pragma unroll
        for (int ct = 0; ct < 8; ct++) {
            float v = acc[ct][gi];
            if (ok) xw[(size_t)rr * FEAT + ct * 16 + r] = (_Float16)v;
            ps[ct >> 1] += v * asv[ct];
            pd[ct >> 1] += v * adv[ct];
        }
#pragma unroll
        for (int h = 0; h < 4; h++) {
#pragma unroll
            for (int m = 1; m < 16; m <<= 1) {
                ps[h] += __shfl_xor(ps[h], m);
                pd[h] += __shfl_xor(pd[h], m);
            }
        }
        if (ok) {
            if (r < 4)      ssrc[rr * HEADS + r] = ps[r];
            else if (r < 8) sdst[rr * HEADS + (r - 4)] = pd[r - 4];
        }
    }
}

// ---------------------------------------------------------------------------
// Single-pass edge softmax+aggregate, one wave per node, 4 edge slots.
// lane = slot(=lane/16) x q(=lane%16, channel octet 8q..8q+7).
// Per edge: 16 lanes x 16 B (fp16) = full 256 B row; 4 edges in flight per
// wave. Self-loop folded in here (slot 0 prologue) -- not stored in CSR.
// No max-subtraction (scores O(+-6), fp32 exp safe). Slot-fold:
// shfl_xor 16,32. Head-mean (final): shfl_xor 4,8. Zero LDS, zero barriers.
// ---------------------------------------------------------------------------
__global__ __launch_bounds__(256) void edge_agg(const _Float16* __restrict__ xw,
                                                const float* __restrict__ ssrc,
                                                const float* __restrict__ sdst,
                                                const int* __restrict__ rowptr,
                                                const int* __restrict__ ssorted,
                                                const float* __restrict__ bias,
                                                float* __restrict__ out,
                                                int final_layer, int Nn) {
    int wid = blockIdx.x * 4 + (threadIdx.x >> 6);   // node index
    if (wid >= Nn) return;
    int lane = threadIdx.x & 63;
    int slot = lane >> 4;       // edge slot 0..3
    int q = lane & 15;          // channel octet (channels 8q..8q+7)
    int qh = q >> 2;            // head of this octet

    int beg = rowptr[wid], end = rowptr[wid + 1];
    float sdh = sdst[wid * HEADS + qh];

    float4 a0 = make_float4(0.f, 0.f, 0.f, 0.f);
    float4 a1 = make_float4(0.f, 0.f, 0.f, 0.f);
    float den = 0.f;

    // self-loop (PyG adds one per node): slot 0 handles it
    if (slot == 0) {
        float v = ssrc[wid * HEADS + qh] + sdh;
        v = v > 0.f ? v : SLOPE * v;
        float w = __expf(v);
        den = w;
        const half8 hv = *(const half8*)(xw + (size_t)wid * FEAT + q * 8);
        a0.x = w * (float)hv[0]; a0.y = w * (float)hv[1];
        a0.z = w * (float)hv[2]; a0.w = w * (float)hv[3];
        a1.x = w * (float)hv[4]; a1.y = w * (float)hv[5];
        a1.z = w * (float)hv[6]; a1.w = w * (float)hv[7];
    }

    for (int i = beg + slot; i < end; i += 4) {
        int s = ssorted[i];                       // broadcast within slot
        float v = ssrc[s * HEADS + qh] + sdh;
        v = v > 0.f ? v : SLOPE * v;
        float w = __expf(v);                      // safe: |v| ~ O(6)
        den += w;
        const half8 hv = *(const half8*)(xw + (size_t)s * FEAT + q * 8);
        a0.x += w * (float)hv[0]; a0.y += w * (float)hv[1];
        a0.z += w * (float)hv[2]; a0.w += w * (float)hv[3];
        a1.x += w * (float)hv[4]; a1.y += w * (float)hv[5];
        a1.z += w * (float)hv[6]; a1.w += w * (float)hv[7];
    }

    // fold the 4 edge slots (lane bits 4,5)
#pragma unroll
    for (int m = 16; m <= 32; m <<= 1) {
        a0.x += __shfl_xor(a0.x, m); a0.y += __shfl_xor(a0.y, m);
        a0.z += __shfl_xor(a0.z, m); a0.w += __shfl_xor(a0.w, m);
        a1.x += __shfl_xor(a1.x, m); a1.y += __shfl_xor(a1.y, m);
        a1.z += __shfl_xor(a1.z, m); a1.w += __shfl_xor(a1.w, m);
        den  += __shfl_xor(den, m);
    }

    float inv = 1.f / den;                        // den>0 (self loop); per-head
    a0.x *= inv; a0.y *= inv; a0.z *= inv; a0.w *= inv;
    a1.x *= inv; a1.y *= inv; a1.z *= inv; a1.w *= inv;

    if (!final_layer) {
        if (lane < 16) {
            const float4 b0 = *(const float4*)(bias + q * 8);
            const float4 b1 = *(const float4*)(bias + q * 8 + 4);
            float4 r0, r1;
            r0.x = a0.x + b0.x; r0.y = a0.y + b0.y; r0.z = a0.z + b0.z; r0.w = a0.w + b0.w;
            r1.x = a1.x + b1.x; r1.y = a1.y + b1.y; r1.z = a1.z + b1.z; r1.w = a1.w + b1.w;
            r0.x = r0.x > 0.f ? r0.x : expm1f(r0.x);
            r0.y = r0.y > 0.f ? r0.y : expm1f(r0.y);
            r0.z = r0.z > 0.f ? r0.z : expm1f(r0.z);
            r0.w = r0.w > 0.f ? r0.w : expm1f(r0.w);
            r1.x = r1.x > 0.f ? r1.x : expm1f(r1.x);
            r1.y = r1.y > 0.f ? r1.y : expm1f(r1.y);
            r1.z = r1.z > 0.f ? r1.z : expm1f(r1.z);
            r1.w = r1.w > 0.f ? r1.w : expm1f(r1.w);
            float4* op = (float4*)(out + (size_t)wid * FEAT + q * 8);
            op[0] = r0; op[1] = r1;
        }
    } else {
        // head-mean: same within-head channels sit at lanes q, q^4, q^8 (bits 2,3)
#pragma unroll
        for (int m = 4; m <= 8; m <<= 1) {
            a0.x += __shfl_xor(a0.x, m); a0.y += __shfl_xor(a0.y, m);
            a0.z += __shfl_xor(a0.z, m); a0.w += __shfl_xor(a0.w, m);
            a1.x += __shfl_xor(a1.x, m); a1.y += __shfl_xor(a1.y, m);
            a1.z += __shfl_xor(a1.z, m); a1.w += __shfl_xor(a1.w, m);
        }
        if (lane < 4) {
            const float4 b0 = *(const float4*)(bias + q * 8);
            const float4 b1 = *(const float4*)(bias + q * 8 + 4);
            float4 r0, r1;
            r0.x = a0.x * 0.25f + b0.x; r0.y = a0.y * 0.25f + b0.y;
            r0.z = a0.z * 0.25f + b0.z; r0.w = a0.w * 0.25f + b0.w;
            r1.x = a1.x * 0.25f + b1.x; r1.y = a1.y * 0.25f + b1.y;
            r1.z = a1.z * 0.25f + b1.z; r1.w = a1.w * 0.25f + b1.w;
            float4* op = (float4*)(out + (size_t)wid * HID + q * 8);
            op[0] = r0; op[1] = r1;
        }
    }
}

// ---------------------------------------------------------------------------
// Launch
// ---------------------------------------------------------------------------
extern "C" void kernel_launch(void* const* d_in, const int* in_sizes, int n_in,
                              void* d_out, int out_size, void* d_ws, size_t ws_size,
                              hipStream_t stream) {
    const float* x   = (const float*)d_in[0];
    const int* eidx  = (const int*)d_in[1];
    const float* W1  = (const float*)d_in[2];
    const float* as1 = (const float*)d_in[3];
    const float* ad1 = (const float*)d_in[4];
    const float* b1  = (const float*)d_in[5];
    const float* W2  = (const float*)d_in[6];
    const float* as2 = (const float*)d_in[7];
    const float* ad2 = (const float*)d_in[8];
    const float* b2  = (const float*)d_in[9];
    const float* W3  = (const float*)d_in[10];
    const float* as3 = (const float*)d_in[11];
    const float* ad3 = (const float*)d_in[12];
    const float* b3  = (const float*)d_in[13];

    const int Nn = in_sizes[0] / FEAT;   // 100000
    const int E  = in_sizes[1] / 2;      // 1200000

    char* w = (char*)d_ws;
    size_t off = 0;
    auto alloc = [&](size_t bytes) {
        void* p = w + off;
        off += (bytes + 255) & ~(size_t)255;
        return p;
    };
    float* bufB   = (float*)alloc((size_t)Nn * FEAT * 4);     // inter-layer fp32
    _Float16* xwh = (_Float16*)alloc((size_t)Nn * FEAT * 2);  // post-GEMM features (fp16)
    float* ssrc   = (float*)alloc((size_t)Nn * HEADS * 4);
    float* sdst   = (float*)alloc((size_t)Nn * HEADS * 4);
    int*   rowptr = (int*)alloc((size_t)(Nn + 1) * 4);
    int*   deg    = (int*)alloc((size_t)Nn * 4);
    int*   rank   = (int*)alloc((size_t)E * 4);
    int*   ssort  = (int*)alloc((size_t)E * 4);
    int*   bsum   = (int*)alloc(64 * 4);
    unsigned short* wth = (unsigned short*)alloc((size_t)3 * FEAT * FEAT * 2);
    unsigned short* wtl = (unsigned short*)alloc((size_t)3 * FEAT * FEAT * 2);
    (void)ws_size;

    // ---- CSR build + all-layer W prep (once)
    hipMemsetAsync(deg, 0, (size_t)Nn * 4, stream);
    hist_kernel<<<(E + 255) / 256, 256, 0, stream>>>(eidx, deg, rank, E);
    prep_w3<<<(3 * FEAT * FEAT + 255) / 256, 256, 0, stream>>>(W1, W2, W3, wth, wtl);
    int nscan = (Nn + SCAN_TILE - 1) / SCAN_TILE;
    scan_partial<<<nscan, SCAN_BLK, 0, stream>>>(deg, bsum, Nn);
    scan_bsum<<<1, 64, 0, stream>>>(bsum, nscan);
    scan_final<<<nscan, SCAN_BLK, 0, stream>>>(deg, bsum, rowptr, Nn);
    scatter_kernel<<<(E + 255) / 256, 256, 0, stream>>>(eidx, rank, rowptr, ssort, E);

    const int gemm_grid = (Nn + 63) / 64;
    const int agg_grid  = (Nn + 3) / 4;

    const float* as[3] = {as1, as2, as3};
    const float* ad[3] = {ad1, ad2, ad3};
    const float* bs[3] = {b1, b2, b3};

    const float* cur_in = x;
    for (int L = 0; L < 3; L++) {
        float* nxt = (L == 2) ? (float*)d_out : bufB;
        gemm_mfma<<<gemm_grid, 256, 0, stream>>>(cur_in,
                                                 wth + (size_t)L * FEAT * FEAT,
                                                 wtl + (size_t)L * FEAT * FEAT,
                                                 as[L], ad[L], xwh, ssrc, sdst, Nn);
        edge_agg<<<agg_grid, 256, 0, stream>>>(xwh, ssrc, sdst, rowptr, ssort,
                                               bs[L], nxt, L == 2, Nn);
        cur_in = bufB;
    }
}

// Round 3
// 485.575 us; speedup vs baseline: 1.3977x; 1.0460x over previous
//
#include <hip/hip_runtime.h>
#include <math.h>

#define HEADS 4
#define HID 32
#define FEAT 128   // HEADS*HID == IN == hidden width everywhere
#define SLOPE 0.2f

typedef __attribute__((ext_vector_type(4))) float frag_cd;  // 4 fp32
typedef __attribute__((ext_vector_type(8))) _Float16 half8; // 16B of fp16

// ---------------------------------------------------------------------------
// CSR build. hist's atomicAdd return value IS the edge's rank within its
// destination bucket -> scatter needs no atomic (no dependent atomic->store
// chain). Self-loops are folded into edge_agg directly (no CSR slot).
// ---------------------------------------------------------------------------

__global__ void hist_kernel(const int* __restrict__ edge_index, int* __restrict__ deg,
                            int* __restrict__ rank, int E) {
    int e = blockIdx.x * 256 + threadIdx.x;
    if (e < E) rank[e] = atomicAdd(&deg[edge_index[E + e]], 1);
}

#define SCAN_BLK 1024
#define SCAN_CHUNK 4
#define SCAN_TILE (SCAN_BLK * SCAN_CHUNK)

__global__ __launch_bounds__(SCAN_BLK) void scan_partial(const int* __restrict__ deg,
                                                         int* __restrict__ bsum, int Nn) {
    __shared__ int red[SCAN_BLK];
    int t = threadIdx.x;
    int base = blockIdx.x * SCAN_TILE + t * SCAN_CHUNK;
    int s = 0;
#pragma unroll
    for (int i = 0; i < SCAN_CHUNK; i++) {
        int idx = base + i;
        if (idx < Nn) s += deg[idx];
    }
    red[t] = s;
    __syncthreads();
    for (int off = SCAN_BLK / 2; off >= 1; off >>= 1) {
        if (t < off) red[t] += red[t + off];
        __syncthreads();
    }
    if (t == 0) bsum[blockIdx.x] = red[0];
}

__global__ __launch_bounds__(64) void scan_bsum(int* __restrict__ bsum, int nb) {
    int t = threadIdx.x;
    int v = (t < nb) ? bsum[t] : 0;
    int orig = v;
#pragma unroll
    for (int off = 1; off < 64; off <<= 1) {
        int u = __shfl_up(v, off);
        if (t >= off) v += u;
    }
    if (t < nb) bsum[t] = v - orig;
}

__global__ __launch_bounds__(SCAN_BLK) void scan_final(const int* __restrict__ deg,
                                                       const int* __restrict__ bsum,
                                                       int* __restrict__ rowptr, int Nn) {
    __shared__ int sums[SCAN_BLK];
    int t = threadIdx.x;
    int base = blockIdx.x * SCAN_TILE + t * SCAN_CHUNK;
    int loc[SCAN_CHUNK];
    int s = 0;
#pragma unroll
    for (int i = 0; i < SCAN_CHUNK; i++) {
        int idx = base + i;
        int d = (idx < Nn) ? deg[idx] : 0;
        loc[i] = s;
        s += d;
    }
    sums[t] = s;
    __syncthreads();
    for (int off = 1; off < SCAN_BLK; off <<= 1) {
        int v = (t >= off) ? sums[t - off] : 0;
        __syncthreads();
        sums[t] += v;
        __syncthreads();
    }
    int texcl = (t == 0) ? 0 : sums[t - 1];
    int offn = bsum[blockIdx.x] + texcl;
#pragma unroll
    for (int i = 0; i < SCAN_CHUNK; i++) {
        int idx = base + i;
        if (idx < Nn) rowptr[idx] = offn + loc[i];
    }
    if (blockIdx.x == gridDim.x - 1 && t == SCAN_BLK - 1)
        rowptr[Nn] = offn + s;
}

// No atomic: position = rowptr[dst] + precomputed rank. Bijective per bucket.
__global__ void scatter_kernel(const int* __restrict__ edge_index,
                               const int* __restrict__ rank,
                               const int* __restrict__ rowptr,
                               int* __restrict__ ssorted, int E) {
    int e = blockIdx.x * 256 + threadIdx.x;
    if (e < E) {
        int d = edge_index[E + e];
        ssorted[rowptr[d] + rank[e]] = edge_index[e];
    }
}

// ---------------------------------------------------------------------------
// W prep, all 3 layers in one launch: split fp32 W[k][c] into fp16 hi/lo
// (hi = RNE fp16, lo = residual, exactly representable for |W|~0.1).
// Fragment-friendly transposed: wt[L][ (g*128 + c)*8 + j ] = W_L[g*8 + j][c]
// ---------------------------------------------------------------------------
__global__ void prep_w3(const float* __restrict__ W1, const float* __restrict__ W2,
                        const float* __restrict__ W3,
                        _Float16* __restrict__ wt_hi,
                        _Float16* __restrict__ wt_lo) {
    int idx = blockIdx.x * 256 + threadIdx.x;
    if (idx >= 3 * FEAT * FEAT) return;
    int L = idx / (FEAT * FEAT);
    int r = idx - L * FEAT * FEAT;
    const float* W = (L == 0) ? W1 : (L == 1) ? W2 : W3;
    int c = r >> 7, k = r & 127;
    float v = W[(size_t)k * FEAT + c];
    _Float16 hi = (_Float16)v;
    _Float16 lo = (_Float16)(v - (float)hi);
    int g = k >> 3, j = k & 7;
    size_t o = (size_t)L * FEAT * FEAT + ((size_t)g * FEAT + c) * 8 + j;
    wt_hi[o] = hi;
    wt_lo[o] = lo;
}

// ---------------------------------------------------------------------------
// GEMM via native fp16 MFMA 16x16x32 (W split fp16 hi/lo = near-fp32 W
// accuracy; A is fp16 (layers 2,3: zero conversion VALU) or fp32 (layer 1:
// 8x v_cvt_f16_f32 per k-step)). 2 MFMAs per tile (was 3 with bf16 split).
// Fused epilogue: fp16 feature matrix xw + per-node attn score halves.
// ---------------------------------------------------------------------------
template <int A16>
__global__ __launch_bounds__(256) void gemm_mfma(const float* __restrict__ Af,
                                                 const _Float16* __restrict__ Ah,
                                                 const _Float16* __restrict__ wt_hi,
                                                 const _Float16* __restrict__ wt_lo,
                                                 const float* __restrict__ a_s,
                                                 const float* __restrict__ a_d,
                                                 _Float16* __restrict__ xw,
                                                 float* __restrict__ ssrc,
                                                 float* __restrict__ sdst,
                                                 int nrows) {
    int tid = threadIdx.x;
    int wave = tid >> 6, lane = tid & 63;
    int r = lane & 15;     // A-row (load) / D-col (store) index within tile
    int q = lane >> 4;     // k-quad (A/B) / row-quad (D)
    int rowbase = blockIdx.x * 64 + wave * 16;

    int arow = rowbase + r;
    if (arow >= nrows) arow = nrows - 1;

    frag_cd acc[8];
#pragma unroll
    for (int ct = 0; ct < 8; ct++) acc[ct] = (frag_cd){0.f, 0.f, 0.f, 0.f};

#pragma unroll
    for (int k0 = 0; k0 < FEAT; k0 += 32) {
        int kk = k0 + q * 8;
        half8 a;
        if (A16) {
            a = *(const half8*)(Ah + (size_t)arow * FEAT + kk);
        } else {
            const float* arowp = Af + (size_t)arow * FEAT;
            float4 a0 = *(const float4*)(arowp + kk);
            float4 a1 = *(const float4*)(arowp + kk + 4);
            a[0] = (_Float16)a0.x; a[1] = (_Float16)a0.y;
            a[2] = (_Float16)a0.z; a[3] = (_Float16)a0.w;
            a[4] = (_Float16)a1.x; a[5] = (_Float16)a1.y;
            a[6] = (_Float16)a1.z; a[7] = (_Float16)a1.w;
        }
        int g = kk >> 3;
#pragma unroll
        for (int ct = 0; ct < 8; ct++) {
            int c = ct * 16 + r;
            const half8 bhi = *(const half8*)(wt_hi + ((size_t)g * FEAT + c) * 8);
            const half8 blo = *(const half8*)(wt_lo + ((size_t)g * FEAT + c) * 8);
            acc[ct] = __builtin_amdgcn_mfma_f32_16x16x32_f16(a, bhi, acc[ct], 0, 0, 0);
            acc[ct] = __builtin_amdgcn_mfma_f32_16x16x32_f16(a, blo, acc[ct], 0, 0, 0);
        }
    }

    float asv[8], adv[8];
#pragma unroll
    for (int ct = 0; ct < 8; ct++) {
        asv[ct] = a_s[ct * 16 + r];
        adv[ct] = a_d[ct * 16 + r];
    }

    // D layout: col = ct*16 + r, row = q*4 + gi  [m89-verified]
#pragma unroll
    for (int gi = 0; gi < 4; gi++) {
        int rr = rowbase + q * 4 + gi;
        bool ok = rr < nrows;
        float ps[4] = {0.f, 0.f, 0.f, 0.f}, pd[4] = {0.f, 0.f, 0.f, 0.f};
#pragma unroll
        for (int ct = 0; ct < 8; ct++) {
            float v = acc[ct][gi];
            if (ok) xw[(size_t)rr * FEAT + ct * 16 + r] = (_Float16)v;
            ps[ct >> 1] += v * asv[ct];
            pd[ct >> 1] += v * adv[ct];
        }
#pragma unroll
        for (int h = 0; h < 4; h++) {
#pragma unroll
            for (int m = 1; m < 16; m <<= 1) {
                ps[h] += __shfl_xor(ps[h], m);
                pd[h] += __shfl_xor(pd[h], m);
            }
        }
        if (ok) {
            if (r < 4)      ssrc[rr * HEADS + r] = ps[r];
            else if (r < 8) sdst[rr * HEADS + (r - 4)] = pd[r - 4];
        }
    }
}

// ---------------------------------------------------------------------------
// Single-pass edge softmax+aggregate, one wave per node, 4 edge slots.
// lane = slot(=lane/16) x q(=lane%16, channel octet 8q..8q+7).
// Per edge: 16 lanes x 16 B (fp16) = full 256 B row; 4 edges in flight per
// wave. Self-loop folded in here (slot 0 prologue) -- not stored in CSR.
// Edge loop is software-pipelined one iteration deep: ssorted[i+4] and the
// next edge's ssrc/xw loads are issued before the current edge's gather is
// consumed (cuts the 2-chained-load critical path to ~1).
// Non-final output is stored fp16 (bufB, read natively by the fp16 GEMM).
// ---------------------------------------------------------------------------
__global__ __launch_bounds__(256) void edge_agg(const _Float16* __restrict__ xw,
                                                const float* __restrict__ ssrc,
                                                const float* __restrict__ sdst,
                                                const int* __restrict__ rowptr,
                                                const int* __restrict__ ssorted,
                                                const float* __restrict__ bias,
                                                float* __restrict__ out,
                                                _Float16* __restrict__ outh,
                                                int final_layer, int Nn) {
    int wid = blockIdx.x * 4 + (threadIdx.x >> 6);   // node index
    if (wid >= Nn) return;
    int lane = threadIdx.x & 63;
    int slot = lane >> 4;       // edge slot 0..3
    int q = lane & 15;          // channel octet (channels 8q..8q+7)
    int qh = q >> 2;            // head of this octet

    int beg = rowptr[wid], end = rowptr[wid + 1];
    float sdh = sdst[wid * HEADS + qh];

    float4 a0 = make_float4(0.f, 0.f, 0.f, 0.f);
    float4 a1 = make_float4(0.f, 0.f, 0.f, 0.f);
    float den = 0.f;

    // self-loop (PyG adds one per node): slot 0 handles it
    if (slot == 0) {
        float v = ssrc[wid * HEADS + qh] + sdh;
        v = v > 0.f ? v : SLOPE * v;
        float w = __expf(v);
        den = w;
        const half8 hv = *(const half8*)(xw + (size_t)wid * FEAT + q * 8);
        a0.x = w * (float)hv[0]; a0.y = w * (float)hv[1];
        a0.z = w * (float)hv[2]; a0.w = w * (float)hv[3];
        a1.x = w * (float)hv[4]; a1.y = w * (float)hv[5];
        a1.z = w * (float)hv[6]; a1.w = w * (float)hv[7];
    }

    // pipelined edge loop
    int i = beg + slot;
    bool haveC = (i < end);
    float scC = 0.f;
    half8 hvC = (half8)(_Float16)0.f;
    if (haveC) {
        int sC = ssorted[i];
        scC = ssrc[sC * HEADS + qh];
        hvC = *(const half8*)(xw + (size_t)sC * FEAT + q * 8);
    }
    while (haveC) {
        int i2 = i + 4;
        bool haveN = (i2 < end);
        int sN = 0;
        if (haveN) sN = ssorted[i2];              // issue next index load first
        // consume current score (in flight since last iteration)
        float v = scC + sdh;
        v = v > 0.f ? v : SLOPE * v;
        float w = __expf(v);                      // safe: |v| ~ O(6)
        den += w;
        // issue next edge's loads (dependent only on sN)
        float scN = 0.f;
        half8 hvN = (half8)(_Float16)0.f;
        if (haveN) {
            scN = ssrc[sN * HEADS + qh];
            hvN = *(const half8*)(xw + (size_t)sN * FEAT + q * 8);
        }
        // consume current gather (in flight since last iteration)
        a0.x += w * (float)hvC[0]; a0.y += w * (float)hvC[1];
        a0.z += w * (float)hvC[2]; a0.w += w * (float)hvC[3];
        a1.x += w * (float)hvC[4]; a1.y += w * (float)hvC[5];
        a1.z += w * (float)hvC[6]; a1.w += w * (float)hvC[7];
        i = i2; haveC = haveN; scC = scN; hvC = hvN;
    }

    // fold the 4 edge slots (lane bits 4,5)
#pragma unroll
    for (int m = 16; m <= 32; m <<= 1) {
        a0.x += __shfl_xor(a0.x, m); a0.y += __shfl_xor(a0.y, m);
        a0.z += __shfl_xor(a0.z, m); a0.w += __shfl_xor(a0.w, m);
        a1.x += __shfl_xor(a1.x, m); a1.y += __shfl_xor(a1.y, m);
        a1.z += __shfl_xor(a1.z, m); a1.w += __shfl_xor(a1.w, m);
        den  += __shfl_xor(den, m);
    }

    float inv = 1.f / den;                        // den>0 (self loop); per-head
    a0.x *= inv; a0.y *= inv; a0.z *= inv; a0.w *= inv;
    a1.x *= inv; a1.y *= inv; a1.z *= inv; a1.w *= inv;

    if (!final_layer) {
        if (lane < 16) {
            const float4 b0 = *(const float4*)(bias + q * 8);
            const float4 b1 = *(const float4*)(bias + q * 8 + 4);
            float4 r0, r1;
            r0.x = a0.x + b0.x; r0.y = a0.y + b0.y; r0.z = a0.z + b0.z; r0.w = a0.w + b0.w;
            r1.x = a1.x + b1.x; r1.y = a1.y + b1.y; r1.z = a1.z + b1.z; r1.w = a1.w + b1.w;
            r0.x = r0.x > 0.f ? r0.x : expm1f(r0.x);
            r0.y = r0.y > 0.f ? r0.y : expm1f(r0.y);
            r0.z = r0.z > 0.f ? r0.z : expm1f(r0.z);
            r0.w = r0.w > 0.f ? r0.w : expm1f(r0.w);
            r1.x = r1.x > 0.f ? r1.x : expm1f(r1.x);
            r1.y = r1.y > 0.f ? r1.y : expm1f(r1.y);
            r1.z = r1.z > 0.f ? r1.z : expm1f(r1.z);
            r1.w = r1.w > 0.f ? r1.w : expm1f(r1.w);
            half8 hv;
            hv[0] = (_Float16)r0.x; hv[1] = (_Float16)r0.y;
            hv[2] = (_Float16)r0.z; hv[3] = (_Float16)r0.w;
            hv[4] = (_Float16)r1.x; hv[5] = (_Float16)r1.y;
            hv[6] = (_Float16)r1.z; hv[7] = (_Float16)r1.w;
            *(half8*)(outh + (size_t)wid * FEAT + q * 8) = hv;
        }
    } else {
        // head-mean: same within-head channels sit at lanes q, q^4, q^8 (bits 2,3)
#pragma unroll
        for (int m = 4; m <= 8; m <<= 1) {
            a0.x += __shfl_xor(a0.x, m); a0.y += __shfl_xor(a0.y, m);
            a0.z += __shfl_xor(a0.z, m); a0.w += __shfl_xor(a0.w, m);
            a1.x += __shfl_xor(a1.x, m); a1.y += __shfl_xor(a1.y, m);
            a1.z += __shfl_xor(a1.z, m); a1.w += __shfl_xor(a1.w, m);
        }
        if (lane < 4) {
            const float4 b0 = *(const float4*)(bias + q * 8);
            const float4 b1 = *(const float4*)(bias + q * 8 + 4);
            float4 r0, r1;
            r0.x = a0.x * 0.25f + b0.x; r0.y = a0.y * 0.25f + b0.y;
            r0.z = a0.z * 0.25f + b0.z; r0.w = a0.w * 0.25f + b0.w;
            r1.x = a1.x * 0.25f + b1.x; r1.y = a1.y * 0.25f + b1.y;
            r1.z = a1.z * 0.25f + b1.z; r1.w = a1.w * 0.25f + b1.w;
            float4* op = (float4*)(out + (size_t)wid * HID + q * 8);
            op[0] = r0; op[1] = r1;
        }
    }
}

// ---------------------------------------------------------------------------
// Launch
// ---------------------------------------------------------------------------
extern "C" void kernel_launch(void* const* d_in, const int* in_sizes, int n_in,
                              void* d_out, int out_size, void* d_ws, size_t ws_size,
                              hipStream_t stream) {
    const float* x   = (const float*)d_in[0];
    const int* eidx  = (const int*)d_in[1];
    const float* W1  = (const float*)d_in[2];
    const float* as1 = (const float*)d_in[3];
    const float* ad1 = (const float*)d_in[4];
    const float* b1  = (const float*)d_in[5];
    const float* W2  = (const float*)d_in[6];
    const float* as2 = (const float*)d_in[7];
    const float* ad2 = (const float*)d_in[8];
    const float* b2  = (const float*)d_in[9];
    const float* W3  = (const float*)d_in[10];
    const float* as3 = (const float*)d_in[11];
    const float* ad3 = (const float*)d_in[12];
    const float* b3  = (const float*)d_in[13];

    const int Nn = in_sizes[0] / FEAT;   // 100000
    const int E  = in_sizes[1] / 2;      // 1200000

    char* w = (char*)d_ws;
    size_t off = 0;
    auto alloc = [&](size_t bytes) {
        void* p = w + off;
        off += (bytes + 255) & ~(size_t)255;
        return p;
    };
    _Float16* bufB = (_Float16*)alloc((size_t)Nn * FEAT * 2); // inter-layer fp16
    _Float16* xwh  = (_Float16*)alloc((size_t)Nn * FEAT * 2); // post-GEMM features (fp16)
    float* ssrc   = (float*)alloc((size_t)Nn * HEADS * 4);
    float* sdst   = (float*)alloc((size_t)Nn * HEADS * 4);
    int*   rowptr = (int*)alloc((size_t)(Nn + 1) * 4);
    int*   deg    = (int*)alloc((size_t)Nn * 4);
    int*   rank   = (int*)alloc((size_t)E * 4);
    int*   ssort  = (int*)alloc((size_t)E * 4);
    int*   bsum   = (int*)alloc(64 * 4);
    _Float16* wth = (_Float16*)alloc((size_t)3 * FEAT * FEAT * 2);
    _Float16* wtl = (_Float16*)alloc((size_t)3 * FEAT * FEAT * 2);
    (void)ws_size;

    // ---- CSR build + all-layer W prep (once)
    hipMemsetAsync(deg, 0, (size_t)Nn * 4, stream);
    hist_kernel<<<(E + 255) / 256, 256, 0, stream>>>(eidx, deg, rank, E);
    prep_w3<<<(3 * FEAT * FEAT + 255) / 256, 256, 0, stream>>>(W1, W2, W3, wth, wtl);
    int nscan = (Nn + SCAN_TILE - 1) / SCAN_TILE;
    scan_partial<<<nscan, SCAN_BLK, 0, stream>>>(deg, bsum, Nn);
    scan_bsum<<<1, 64, 0, stream>>>(bsum, nscan);
    scan_final<<<nscan, SCAN_BLK, 0, stream>>>(deg, bsum, rowptr, Nn);
    scatter_kernel<<<(E + 255) / 256, 256, 0, stream>>>(eidx, rank, rowptr, ssort, E);

    const int gemm_grid = (Nn + 63) / 64;
    const int agg_grid  = (Nn + 3) / 4;

    const float* as[3] = {as1, as2, as3};
    const float* ad[3] = {ad1, ad2, ad3};
    const float* bs[3] = {b1, b2, b3};

    for (int L = 0; L < 3; L++) {
        if (L == 0) {
            gemm_mfma<0><<<gemm_grid, 256, 0, stream>>>(x, (const _Float16*)nullptr,
                                                        wth, wtl,
                                                        as[0], ad[0], xwh, ssrc, sdst, Nn);
        } else {
            gemm_mfma<1><<<gemm_grid, 256, 0, stream>>>((const float*)nullptr, bufB,
                                                        wth + (size_t)L * FEAT * FEAT,
                                                        wtl + (size_t)L * FEAT * FEAT,
                                                        as[L], ad[L], xwh, ssrc, sdst, Nn);
        }
        edge_agg<<<agg_grid, 256, 0, stream>>>(xwh, ssrc, sdst, rowptr, ssort,
                                               bs[L], (L == 2) ? (float*)d_out : nullptr,
                                               bufB, L == 2, Nn);
    }
}